// Round 8
// baseline (275.889 us; speedup 1.0000x reference)
//
#include <hip/hip_runtime.h>
#include <hip/hip_bf16.h>

// Problem constants (from reference)
#define Hh    100
#define NN    1024     // B*L
#define BB    64
#define LL    16
#define EE    2048
#define NNODE 40000

#define KP    128      // K padded to 4 MFMA steps of 32
#define BSPL  4        // b-loop split across blockIdx.y
#define BPB   (BB / BSPL)
#define PFR   12       // fragments per panel: f = t*4+ks, t in 0..2, ks in 0..3
#define PPAN  (PFR * 64 * 8)   // u16 per panel (6144)

typedef unsigned short u16;
typedef __attribute__((ext_vector_type(8))) short short8;   // 8 bf16 = 4 VGPRs
typedef __attribute__((ext_vector_type(4))) float f32x4;    // MFMA C/D

__device__ __forceinline__ float bf2f(u16 u) {
    union { unsigned int i; float f; } v;
    v.i = ((unsigned int)u) << 16;
    return v.f;
}

__device__ __forceinline__ u16 f2bf(float f) {
    unsigned int x = __float_as_uint(f);
    unsigned int lsb = (x >> 16) & 1u;
    x += 0x7fffu + lsb;              // round-to-nearest-even
    return (u16)(x >> 16);
}

__device__ __forceinline__ float sigmoidf_(float x) {
    return 1.0f / (1.0f + expf(-x));
}

template <bool BF>
__device__ __forceinline__ float ldv(const void* p, size_t i) {
    if (BF) return bf2f(((const u16*)p)[i]);
    return ((const float*)p)[i];
}
__device__ __forceinline__ float ldvf(int flag, const void* p, size_t i) {
    return flag ? ldv<true>(p, i) : ldv<false>(p, i);
}

// ---------------------------------------------------------------------------
// k_cvt: per-block dtype self-detect + convert/transpose small float tensors
// to fp32 in ws (gru/att matrices TRANSPOSED for coalesced reads).
template <bool BF>
__device__ void cvt_impl(int t,
                         const void* ew, const void* ggc, const void* wih, const void* whh,
                         const void* bih, const void* bhh, const void* W1w, const void* W1b,
                         const void* W2w, const void* W2b, const void* Wtw, const void* Wtb,
                         const void* qw, const void* qb, const void* W3w, const void* W3b,
                         float* __restrict__ W) {
    const void* src; int si; int doff; int di;
    if      (t <   2048) { src = ew;  si = t;          doff = 0;      di = si; }
    else if (t <  12048) { src = ggc; si = t - 2048;   doff = 2048;   di = si; }                      // row-major (k_gm)
    else if (t <  42048) { src = wih; si = t - 12048;  doff = 12048;  di = (si % 100) * 300 + si / 100; }   // T
    else if (t <  72048) { src = whh; si = t - 42048;  doff = 42048;  di = (si % 100) * 300 + si / 100; }   // T
    else if (t <  72348) { src = bih; si = t - 72048;  doff = 72048;  di = si; }
    else if (t <  72648) { src = bhh; si = t - 72348;  doff = 72352;  di = si; }
    else if (t <  82648) { src = W1w; si = t - 72648;  doff = 72656;  di = (si % 100) * 100 + si / 100; }   // T
    else if (t <  82748) { src = W1b; si = t - 82648;  doff = 82656;  di = si; }
    else if (t <  92748) { src = W2w; si = t - 82748;  doff = 82768;  di = (si % 100) * 100 + si / 100; }   // T
    else if (t <  92848) { src = W2b; si = t - 92748;  doff = 92768;  di = si; }
    else if (t < 102848) { src = Wtw; si = t - 92848;  doff = 92880;  di = (si % 100) * 100 + si / 100; }   // T
    else if (t < 102948) { src = Wtb; si = t - 102848; doff = 102880; di = si; }
    else if (t < 103048) { src = qw;  si = t - 102948; doff = 102992; di = si; }
    else if (t < 103049) { src = qb;  si = t - 103048; doff = 103104; di = si; }
    else if (t < 123049) { src = W3w; si = t - 103049; doff = 103120; di = (si % 200) * 100 + si / 200; }   // T
    else                 { src = W3b; si = t - 123049; doff = 123120; di = si; }
    W[doff + di] = ldv<BF>(src, si);
}

__global__ void __launch_bounds__(256) k_cvt(const void* embed_raw, int* __restrict__ flag,
                      const void* ew, const void* ggc, const void* wih, const void* whh,
                      const void* bih, const void* bhh, const void* W1w, const void* W1b,
                      const void* W2w, const void* W2b, const void* Wtw, const void* Wtb,
                      const void* qw, const void* qb, const void* W3w, const void* W3b,
                      float* __restrict__ W) {
    __shared__ int cnt;
    if (threadIdx.x == 0) cnt = 0;
    __syncthreads();
    int bad = 0;
    const u16* eb = (const u16*)embed_raw;
    for (int i = threadIdx.x; i < 4096; i += 256) {
        float v = bf2f(eb[i]);
        if (!(fabsf(v) <= 0.5f)) bad++;   // counts NaN too
    }
    if (bad) atomicAdd(&cnt, bad);
    __syncthreads();
    const bool bf = (cnt == 0);
    if (blockIdx.x == 0 && threadIdx.x == 0) flag[0] = bf ? 1 : 0;
    int t = blockIdx.x * 256 + threadIdx.x;
    if (t >= 123149) return;
    if (bf) cvt_impl<true >(t, ew, ggc, wih, whh, bih, bhh, W1w, W1b, W2w, W2b, Wtw, Wtb, qw, qb, W3w, W3b, W);
    else    cvt_impl<false>(t, ew, ggc, wih, whh, bih, bhh, W1w, W1b, W2w, W2b, Wtw, Wtb, qw, qb, W3w, W3b, W);
}

// ---------------------------------------------------------------------------
// k_gm: fused embed-gather + m = h0 @ ggc. 8 node-rows per block; h0 never
// hits global memory.
__global__ void __launch_bounds__(256) k_gm(const int* __restrict__ flag,
                                            const int* __restrict__ x,
                                            const void* __restrict__ embed,
                                            const float* __restrict__ ggc_w,
                                            float* __restrict__ m) {
    __shared__ float W[Hh * Hh];
    __shared__ float H[8 * Hh];
    const int tid = threadIdx.x;
    const int fl = flag[0];
    const int r0 = blockIdx.x * 8;
    for (int idx = tid; idx < Hh * Hh; idx += 256) W[idx] = ggc_w[idx];
    for (int idx = tid; idx < 8 * Hh; idx += 256) {
        int i = idx / Hh, j = idx - i * Hh;
        H[idx] = ldvf(fl, embed, (size_t)x[r0 + i] * Hh + j);
    }
    __syncthreads();
    for (int idx = tid; idx < 8 * Hh; idx += 256) {
        int i = idx / Hh, j = idx - i * Hh;
        float acc = 0.0f;
#pragma unroll 4
        for (int k = 0; k < Hh; ++k) acc += H[i * Hh + k] * W[k * Hh + j];
        m[(r0 + i) * Hh + j] = acc;
    }
}

// ---------------------------------------------------------------------------
// k_gruatt: one block per session b. Fuses edge scatter-add (block-local edge
// list, LDS atomics), GRU, attention readout, and swizzled-P build.
// P layout: Psw[b][f][lane][e], f=t*4+ks, lane=quad*16+m, e=0..7 ->
// logical P row t*16+m, col ks*32+quad*8+e. Matches k_score's A-frag loads.
__global__ void __launch_bounds__(256) k_gruatt(const int* __restrict__ flag,
                    const int* __restrict__ x, const int* __restrict__ ei,
                    const void* __restrict__ ew, const void* __restrict__ embed,
                    const float* __restrict__ m,
                    const float* __restrict__ wihT, const float* __restrict__ whhT,
                    const float* __restrict__ bih, const float* __restrict__ bhh,
                    const float* __restrict__ W1T, const float* __restrict__ W1b,
                    const float* __restrict__ W2T, const float* __restrict__ W2b,
                    const float* __restrict__ WtT, const float* __restrict__ Wtb,
                    const float* __restrict__ qw, const float* __restrict__ qb,
                    const float* __restrict__ W3T, const float* __restrict__ W3b,
                    u16* __restrict__ P) {
    __shared__ float AGG[LL * Hh];
    __shared__ float H0[LL * Hh];
    __shared__ float V[LL * Hh];
    __shared__ float Q2[LL * Hh];
    __shared__ float VTs[LL * Hh];
    __shared__ float Q1[Hh];
    __shared__ float AL[LL];
    __shared__ float SG[Hh];
    __shared__ float SH[Hh];
    __shared__ int   elist[EE];
    __shared__ float ewl[EE];
    __shared__ int   ecnt;
    const int b = blockIdx.x, tid = threadIdx.x;
    const int fl = flag[0];

    if (tid == 0) ecnt = 0;
    for (int idx = tid; idx < LL * Hh; idx += 256) {
        AGG[idx] = 0.0f;
        int i = idx / Hh, j = idx - i * Hh;
        H0[idx] = ldvf(fl, embed, (size_t)x[b * LL + i] * Hh + j);
    }
    __syncthreads();

    // Phase 1: collect this block's edges
    for (int e = tid; e < EE; e += 256) {
        int d = ei[EE + e];
        if ((d >> 4) == b) {
            int p = atomicAdd(&ecnt, 1);
            elist[p] = ei[e] * LL + (d & 15);
            ewl[p] = ldvf(fl, ew, e);
        }
    }
    __syncthreads();
    const int cnt = ecnt;
    // Phase 2: scatter-add, 2 edges per round, coalesced m-row reads
    for (int base = 0; base < cnt; base += 2) {
        int li = base + tid / Hh;          // tid<200 active
        if (tid < 2 * Hh && li < cnt) {
            int pk = elist[li];
            int src = pk >> 4, d = pk & 15;
            int j = tid % Hh;
            atomicAdd(&AGG[d * Hh + j], ewl[li] * m[src * Hh + j]);
        }
    }
    __syncthreads();

    // GRU: V = h1
    for (int idx = tid; idx < LL * Hh; idx += 256) {
        int i = idx / Hh, j = idx - i * Hh;
        float s_ir = bih[j], s_iz = bih[j + Hh], s_in = bih[j + 2 * Hh];
        float s_hr = bhh[j], s_hz = bhh[j + Hh], s_hn = bhh[j + 2 * Hh];
        for (int k = 0; k < Hh; ++k) {
            float a = AGG[i * Hh + k], h = H0[i * Hh + k];
            const float* wT = wihT + k * 300;
            const float* uT = whhT + k * 300;
            s_ir += a * wT[j];
            s_iz += a * wT[j + 100];
            s_in += a * wT[j + 200];
            s_hr += h * uT[j];
            s_hz += h * uT[j + 100];
            s_hn += h * uT[j + 200];
        }
        float r = sigmoidf_(s_ir + s_hr);
        float z = sigmoidf_(s_iz + s_hz);
        float n = tanhf(s_in + r * s_hn);
        V[idx] = (1.0f - z) * n + z * H0[idx];
    }
    __syncthreads();

    // Attention readout
    for (int idx = tid; idx < LL * Hh; idx += 256) {
        int i = idx / Hh, j = idx - i * Hh;
        float a2 = 0, at = 0;
        for (int k = 0; k < Hh; ++k) {
            float vk = V[i * Hh + k];
            a2 += vk * W2T[k * Hh + j];
            at += vk * WtT[k * Hh + j];
        }
        Q2[idx] = a2 + W2b[j];
        VTs[idx] = at + Wtb[j];
    }
    if (tid < Hh) {
        float a1 = 0;
        for (int k = 0; k < Hh; ++k) a1 += V[(LL - 1) * Hh + k] * W1T[k * Hh + tid];
        Q1[tid] = a1 + W1b[tid];
    }
    __syncthreads();
    if (tid < LL) {
        float acc = 0;
        for (int j = 0; j < Hh; ++j)
            acc += sigmoidf_(Q1[j] + Q2[tid * Hh + j]) * qw[j];
        AL[tid] = acc + qb[0];
    }
    __syncthreads();
    if (tid < Hh) {
        float acc = 0;
#pragma unroll
        for (int l = 0; l < LL; ++l) acc += AL[l] * V[l * Hh + tid];
        SG[tid] = acc;
    }
    __syncthreads();
    if (tid < Hh) {
        float acc = W3b[tid];
        for (int k = 0; k < Hh; ++k) acc += V[(LL - 1) * Hh + k] * W3T[k * Hh + tid];
        for (int k = 0; k < Hh; ++k) acc += SG[k] * W3T[(Hh + k) * Hh + tid];
        SH[tid] = acc;
    }
    __syncthreads();

    // Swizzled P write: 12 frags x 64 lanes x 8 elems
    for (int w = tid; w < PFR * 64; w += 256) {
        int f = w >> 6, lane = w & 63;
        int t = f >> 2, ks = f & 3;
        int mm = lane & 15, qq = lane >> 4;
        int row = t * 16 + mm;
        int col0 = ks * 32 + qq * 8;
        short8 t8;
#pragma unroll
        for (int e = 0; e < 8; ++e) {
            int col = col0 + e;
            float v = 0.0f;
            if (col < Hh) {
                if      (row < 16) v = VTs[row * Hh + col];
                else if (row < 32) v = V[(row - 16) * Hh + col];
                else if (row == 32) v = SH[col];
            }
            t8[e] = (short)f2bf(v);
        }
        *(short8*)&P[((size_t)b * PFR + f) * 512 + lane * 8] = t8;
    }
}

// ---------------------------------------------------------------------------
// k_score v4: no LDS, no barriers in the b-loop. Embed rows = register B-frags
// (loaded once); P panels = A-frags read as 12 coalesced 16B loads from the
// pre-swizzled layout, ping-pong register prefetch across b iterations.
__device__ __forceinline__ short8 load_efrag(const void* embed, bool bf, int j, int k0) {
    short8 v = {0, 0, 0, 0, 0, 0, 0, 0};
    if (j >= NNODE || k0 >= Hh) return v;
    if (bf) {
        const u16* row = (const u16*)embed + (size_t)j * Hh + k0;
        if (k0 + 8 <= Hh) {
            ushort4 a = *(const ushort4*)(row);
            ushort4 b = *(const ushort4*)(row + 4);
            v[0] = (short)a.x; v[1] = (short)a.y; v[2] = (short)a.z; v[3] = (short)a.w;
            v[4] = (short)b.x; v[5] = (short)b.y; v[6] = (short)b.z; v[7] = (short)b.w;
        } else {
            for (int e = 0; e < Hh - k0; ++e) v[e] = (short)row[e];
        }
    } else {
        const float* row = (const float*)embed + (size_t)j * Hh + k0;
        if (k0 + 8 <= Hh) {
            float4 a = *(const float4*)(row);
            float4 b = *(const float4*)(row + 4);
            v[0] = (short)f2bf(a.x); v[1] = (short)f2bf(a.y); v[2] = (short)f2bf(a.z); v[3] = (short)f2bf(a.w);
            v[4] = (short)f2bf(b.x); v[5] = (short)f2bf(b.y); v[6] = (short)f2bf(b.z); v[7] = (short)f2bf(b.w);
        } else {
            for (int e = 0; e < Hh - k0; ++e) v[e] = (short)f2bf(row[e]);
        }
    }
    return v;
}

__global__ void __launch_bounds__(256) k_score(const int* __restrict__ flag,
                                               const void* __restrict__ embed,
                                               const u16* __restrict__ P,
                                               void* __restrict__ out) {
    const int jb = blockIdx.x * 128;
    const int b0 = blockIdx.y * BPB;
    const int tid = threadIdx.x;
    const bool bf = (flag[0] != 0);
    const int wave = tid >> 6, lane = tid & 63;
    const int m = lane & 15, quad = lane >> 4;

    // B fragments: 2 groups of 16 embed rows per wave, loaded once.
    short8 Bf[2][4];
#pragma unroll
    for (int g = 0; g < 2; ++g)
#pragma unroll
        for (int ks = 0; ks < 4; ++ks)
            Bf[g][ks] = load_efrag(embed, bf, jb + wave * 32 + g * 16 + m, ks * 32 + quad * 8);

    // C/D orientation probe (m89-verified expectation: isH1 true).
    short8 pa = {0, 0, 0, 0, 0, 0, 0, 0};
    short8 pb = {0, 0, 0, 0, 0, 0, 0, 0};
    if (quad == 0) {
        pa[0] = (short)f2bf((float)m);
        pb[0] = (short)f2bf(1.0f);
    }
    f32x4 pd = (f32x4){0.0f, 0.0f, 0.0f, 0.0f};
    pd = __builtin_amdgcn_mfma_f32_16x16x32_bf16(pa, pb, pd, 0, 0, 0);
    const bool isH1 =
        (__builtin_amdgcn_readfirstlane(__float_as_uint(pd[1])) == 0x3f800000u);

    auto loadA = [&](short8* A, int b) {
        const u16* Pb = P + (size_t)b * PPAN;
#pragma unroll
        for (int f = 0; f < PFR; ++f)
            A[f] = *(const short8*)&Pb[f * 512 + lane * 8];
    };

    auto compute = [&](const short8* A, int b) {
        f32x4 acc[2][3];
#pragma unroll
        for (int g = 0; g < 2; ++g)
#pragma unroll
            for (int t = 0; t < 3; ++t)
                acc[g][t] = (f32x4){0.0f, 0.0f, 0.0f, 0.0f};
#pragma unroll
        for (int ks = 0; ks < 4; ++ks)
#pragma unroll
            for (int g = 0; g < 2; ++g)
#pragma unroll
                for (int t = 0; t < 3; ++t)
                    acc[g][t] = __builtin_amdgcn_mfma_f32_16x16x32_bf16(A[t * 4 + ks], Bf[g][ks], acc[g][t], 0, 0, 0);

#pragma unroll
        for (int g = 0; g < 2; ++g) {
            if (isH1) {
                // col = lane&15 = n (embed row); row = quad*4+reg = P row
                float mx = fmaxf(fmaxf(acc[g][0][0], acc[g][0][1]), fmaxf(acc[g][0][2], acc[g][0][3]));
                mx = fmaxf(mx, __shfl_xor(mx, 16));
                mx = fmaxf(mx, __shfl_xor(mx, 32));
                float den = 0.0f, num = 0.0f;
#pragma unroll
                for (int r = 0; r < 4; ++r) {
                    float p = __expf(acc[g][0][r] - mx);
                    den += p;
                    num += p * acc[g][1][r];
                }
                den += __shfl_xor(den, 16); num += __shfl_xor(num, 16);
                den += __shfl_xor(den, 32); num += __shfl_xor(num, 32);
                if (quad == 0) {
                    int j = jb + wave * 32 + g * 16 + m;
                    if (j < NNODE) {
                        float z = acc[g][2][0] + num / den;    // sd: P row 0 of tile 2
                        if (bf) ((u16*)out)[(size_t)b * NNODE + j] = f2bf(z);
                        else    ((float*)out)[(size_t)b * NNODE + j] = z;
                    }
                }
            } else {
                float mx[4], den[4], num[4];
#pragma unroll
                for (int r = 0; r < 4; ++r) mx[r] = acc[g][0][r];
#pragma unroll
                for (int s = 1; s <= 8; s <<= 1)
#pragma unroll
                    for (int r = 0; r < 4; ++r) mx[r] = fmaxf(mx[r], __shfl_xor(mx[r], s));
#pragma unroll
                for (int r = 0; r < 4; ++r) {
                    float p = __expf(acc[g][0][r] - mx[r]);
                    den[r] = p;
                    num[r] = p * acc[g][1][r];
                }
#pragma unroll
                for (int s = 1; s <= 8; s <<= 1)
#pragma unroll
                    for (int r = 0; r < 4; ++r) {
                        den[r] += __shfl_xor(den[r], s);
                        num[r] += __shfl_xor(num[r], s);
                    }
                if (m == 0) {
#pragma unroll
                    for (int r = 0; r < 4; ++r) {
                        int j = jb + wave * 32 + g * 16 + quad * 4 + r;
                        if (j < NNODE) {
                            float z = acc[g][2][r] + num[r] / den[r];
                            if (bf) ((u16*)out)[(size_t)b * NNODE + j] = f2bf(z);
                            else    ((float*)out)[(size_t)b * NNODE + j] = z;
                        }
                    }
                }
            }
        }
    };

    short8 A0[PFR], A1[PFR];
    loadA(A0, b0);
#pragma unroll
    for (int bi = 0; bi < BPB; bi += 2) {
        if (bi + 1 < BPB) loadA(A1, b0 + bi + 1);
        compute(A0, b0 + bi);
        if (bi + 2 < BPB) loadA(A0, b0 + bi + 2);
        if (bi + 1 < BPB) compute(A1, b0 + bi + 1);
    }
}

extern "C" void kernel_launch(void* const* d_in, const int* in_sizes, int n_in,
                              void* d_out, int out_size, void* d_ws, size_t ws_size,
                              hipStream_t stream) {
    const int* x      = (const int*)d_in[0];
    const int* ei     = (const int*)d_in[1];
    const void* ew    = d_in[2];
    // d_in[3] batch: unused by reference
    const void* embed = d_in[4];
    const void* ggc   = d_in[5];
    const void* wih   = d_in[6];
    const void* whh   = d_in[7];
    const void* bih   = d_in[8];
    const void* bhh   = d_in[9];
    const void* W1w   = d_in[10];
    const void* W1b   = d_in[11];
    const void* W2w   = d_in[12];
    const void* W2b   = d_in[13];
    const void* Wtw   = d_in[14];
    const void* Wtb   = d_in[15];
    const void* qw    = d_in[16];
    const void* qb    = d_in[17];
    const void* W3w   = d_in[18];
    const void* W3b   = d_in[19];
    float* ws = (float*)d_ws;
    int* flag = (int*)d_ws;          // ws[0]

    // ws layout (floats):
    //   [0..64)           flag + pad
    //   [64..64+123232)   fp32 weight region W (gru/att matrices TRANSPOSED)
    //   [D..)             m (102400) | P bf16 (196608 floats) — disjoint:
    //   k_gruatt reads m and writes P; k_score reads P only.
    float* W = ws + 64;
    float* ggc_f = W + 2048;
    float* wihT  = W + 12048;
    float* whhT  = W + 42048;
    float* bih_f = W + 72048;
    float* bhh_f = W + 72352;
    float* W1T   = W + 72656;
    float* W1b_f = W + 82656;
    float* W2T   = W + 82768;
    float* W2b_f = W + 92768;
    float* WtT   = W + 92880;
    float* Wtb_f = W + 102880;
    float* qw_f  = W + 102992;
    float* qb_f  = W + 103104;
    float* W3T   = W + 103120;
    float* W3b_f = W + 123120;

    float* D     = ws + 123296;
    float* m     = D;                       // 102400 floats
    u16*   P     = (u16*)(D + 102400);      // 393216 u16 = 196608 floats

    k_cvt    <<<dim3(482), dim3(256), 0, stream>>>(embed, flag, ew, ggc, wih, whh, bih, bhh,
                                                   W1w, W1b, W2w, W2b, Wtw, Wtb, qw, qb, W3w, W3b, W);
    k_gm     <<<dim3(128), dim3(256), 0, stream>>>(flag, x, embed, ggc_f, m);
    k_gruatt <<<dim3(64),  dim3(256), 0, stream>>>(flag, x, ei, ew, embed, m,
                                                   wihT, whhT, bih_f, bhh_f,
                                                   W1T, W1b_f, W2T, W2b_f, WtT, Wtb_f,
                                                   qw_f, qb_f, W3T, W3b_f, P);
    k_score  <<<dim3((NNODE + 127) / 128, BSPL), dim3(256), 0, stream>>>(flag, embed, P, d_out);
}

// Round 9
// 241.115 us; speedup vs baseline: 1.1442x; 1.1442x over previous
//
#include <hip/hip_runtime.h>
#include <hip/hip_bf16.h>

// Problem constants (from reference)
#define Hh    100
#define NN    1024     // B*L
#define BB    64
#define LL    16
#define EE    2048
#define NNODE 40000

#define BSPL  4        // b-loop split across blockIdx.y
#define BPB   (BB / BSPL)
#define PFR   12       // fragments per panel: f = t*4+ks, t in 0..2, ks in 0..3
#define PPAN  (PFR * 64 * 8)   // u16 per panel (6144)

typedef unsigned short u16;
typedef __attribute__((ext_vector_type(8))) short short8;   // 8 bf16 = 4 VGPRs
typedef __attribute__((ext_vector_type(4))) float f32x4;    // MFMA C/D

__device__ __forceinline__ float bf2f(u16 u) {
    union { unsigned int i; float f; } v;
    v.i = ((unsigned int)u) << 16;
    return v.f;
}

__device__ __forceinline__ u16 f2bf(float f) {
    unsigned int x = __float_as_uint(f);
    unsigned int lsb = (x >> 16) & 1u;
    x += 0x7fffu + lsb;              // round-to-nearest-even
    return (u16)(x >> 16);
}

__device__ __forceinline__ float sigmoidf_(float x) {
    return 1.0f / (1.0f + expf(-x));
}

template <bool BF>
__device__ __forceinline__ float ldv(const void* p, size_t i) {
    if (BF) return bf2f(((const u16*)p)[i]);
    return ((const float*)p)[i];
}
__device__ __forceinline__ float ldvf(int flag, const void* p, size_t i) {
    return flag ? ldv<true>(p, i) : ldv<false>(p, i);
}

// ---------------------------------------------------------------------------
// k_cvt: per-block dtype self-detect + convert/transpose small float tensors
// to fp32 in ws (gru/att matrices TRANSPOSED for coalesced reads).
template <bool BF>
__device__ void cvt_impl(int t,
                         const void* ew, const void* ggc, const void* wih, const void* whh,
                         const void* bih, const void* bhh, const void* W1w, const void* W1b,
                         const void* W2w, const void* W2b, const void* Wtw, const void* Wtb,
                         const void* qw, const void* qb, const void* W3w, const void* W3b,
                         float* __restrict__ W) {
    const void* src; int si; int doff; int di;
    if      (t <   2048) { src = ew;  si = t;          doff = 0;      di = si; }
    else if (t <  12048) { src = ggc; si = t - 2048;   doff = 2048;   di = si; }                      // row-major (k_gm)
    else if (t <  42048) { src = wih; si = t - 12048;  doff = 12048;  di = (si % 100) * 300 + si / 100; }   // T
    else if (t <  72048) { src = whh; si = t - 42048;  doff = 42048;  di = (si % 100) * 300 + si / 100; }   // T
    else if (t <  72348) { src = bih; si = t - 72048;  doff = 72048;  di = si; }
    else if (t <  72648) { src = bhh; si = t - 72348;  doff = 72352;  di = si; }
    else if (t <  82648) { src = W1w; si = t - 72648;  doff = 72656;  di = (si % 100) * 100 + si / 100; }   // T
    else if (t <  82748) { src = W1b; si = t - 82648;  doff = 82656;  di = si; }
    else if (t <  92748) { src = W2w; si = t - 82748;  doff = 82768;  di = (si % 100) * 100 + si / 100; }   // T
    else if (t <  92848) { src = W2b; si = t - 92748;  doff = 92768;  di = si; }
    else if (t < 102848) { src = Wtw; si = t - 92848;  doff = 92880;  di = (si % 100) * 100 + si / 100; }   // T
    else if (t < 102948) { src = Wtb; si = t - 102848; doff = 102880; di = si; }
    else if (t < 103048) { src = qw;  si = t - 102948; doff = 102992; di = si; }
    else if (t < 103049) { src = qb;  si = t - 103048; doff = 103104; di = si; }
    else if (t < 123049) { src = W3w; si = t - 103049; doff = 103120; di = (si % 200) * 100 + si / 200; }   // T
    else                 { src = W3b; si = t - 123049; doff = 123120; di = si; }
    W[doff + di] = ldv<BF>(src, si);
}

__global__ void __launch_bounds__(256) k_cvt(const void* embed_raw, int* __restrict__ flag,
                      const void* ew, const void* ggc, const void* wih, const void* whh,
                      const void* bih, const void* bhh, const void* W1w, const void* W1b,
                      const void* W2w, const void* W2b, const void* Wtw, const void* Wtb,
                      const void* qw, const void* qb, const void* W3w, const void* W3b,
                      float* __restrict__ W) {
    __shared__ int cnt;
    if (threadIdx.x == 0) cnt = 0;
    __syncthreads();
    int bad = 0;
    const u16* eb = (const u16*)embed_raw;
    for (int i = threadIdx.x; i < 4096; i += 256) {
        float v = bf2f(eb[i]);
        if (!(fabsf(v) <= 0.5f)) bad++;   // counts NaN too
    }
    if (bad) atomicAdd(&cnt, bad);
    __syncthreads();
    const bool bf = (cnt == 0);
    if (blockIdx.x == 0 && threadIdx.x == 0) flag[0] = bf ? 1 : 0;
    int t = blockIdx.x * 256 + threadIdx.x;
    if (t >= 123149) return;
    if (bf) cvt_impl<true >(t, ew, ggc, wih, whh, bih, bhh, W1w, W1b, W2w, W2b, Wtw, Wtb, qw, qb, W3w, W3b, W);
    else    cvt_impl<false>(t, ew, ggc, wih, whh, bih, bhh, W1w, W1b, W2w, W2b, Wtw, Wtb, qw, qb, W3w, W3b, W);
}

// ---------------------------------------------------------------------------
// k_gm: fused embed-gather + m = h0 @ ggc, plus agg zero-init.
__global__ void __launch_bounds__(256) k_gm(const int* __restrict__ flag,
                                            const int* __restrict__ x,
                                            const void* __restrict__ embed,
                                            const float* __restrict__ ggc_w,
                                            float* __restrict__ m,
                                            float* __restrict__ agg) {
    __shared__ float W[Hh * Hh];
    __shared__ float H[8 * Hh];
    const int tid = threadIdx.x;
    const int fl = flag[0];
    const int r0 = blockIdx.x * 8;
    for (int idx = tid; idx < Hh * Hh; idx += 256) W[idx] = ggc_w[idx];
    for (int idx = tid; idx < 8 * Hh; idx += 256) {
        int i = idx / Hh, j = idx - i * Hh;
        H[idx] = ldvf(fl, embed, (size_t)x[r0 + i] * Hh + j);
    }
    // zero agg: 800 elements per block
    for (int idx = tid; idx < 8 * Hh; idx += 256) agg[r0 * Hh + idx] = 0.0f;
    __syncthreads();
    for (int idx = tid; idx < 8 * Hh; idx += 256) {
        int i = idx / Hh, j = idx - i * Hh;
        float acc = 0.0f;
#pragma unroll 4
        for (int k = 0; k < Hh; ++k) acc += H[i * Hh + k] * W[k * Hh + j];
        m[(r0 + i) * Hh + j] = acc;
    }
}

// agg[dst[e]] += ew[e] * m[src[e]]
__global__ void k_scatter(const int* __restrict__ ei, const float* __restrict__ ew,
                          const float* __restrict__ m, float* __restrict__ agg) {
    int t = blockIdx.x * 256 + threadIdx.x;
    if (t >= EE * Hh) return;
    int e = t / Hh, j = t - e * Hh;
    int src = ei[e], dst = ei[EE + e];
    atomicAdd(&agg[dst * Hh + j], ew[e] * m[src * Hh + j]);
}

// GRU cell: h0 re-gathered from embed (no h0 buffer). Transposed weights ->
// coalesced; 400 blocks for latency hiding.
__global__ void k_gru(const int* __restrict__ flag, const int* __restrict__ x,
                      const void* __restrict__ embed,
                      const float* __restrict__ agg,
                      const float* __restrict__ wihT, const float* __restrict__ whhT,
                      const float* __restrict__ bih, const float* __restrict__ bhh,
                      float* __restrict__ h1) {
    int t = blockIdx.x * 256 + threadIdx.x;
    if (t >= NN * Hh) return;
    int i = t / Hh, j = t - i * Hh;
    const int fl = flag[0];
    const size_t erow = (size_t)x[i] * Hh;
    const float* ar = agg + i * Hh;
    float s_ir = bih[j], s_iz = bih[j + Hh], s_in = bih[j + 2 * Hh];
    float s_hr = bhh[j], s_hz = bhh[j + Hh], s_hn = bhh[j + 2 * Hh];
    float h0j = 0.0f;
    for (int k = 0; k < Hh; ++k) {
        float a = ar[k];
        float h = ldvf(fl, embed, erow + k);
        if (k == j) h0j = h;
        const float* wT = wihT + k * 300;
        const float* uT = whhT + k * 300;
        s_ir += a * wT[j];
        s_iz += a * wT[j + 100];
        s_in += a * wT[j + 200];
        s_hr += h * uT[j];
        s_hz += h * uT[j + 100];
        s_hn += h * uT[j + 200];
    }
    float r = sigmoidf_(s_ir + s_hr);
    float z = sigmoidf_(s_iz + s_hz);
    float n = tanhf(s_in + r * s_hn);
    h1[t] = (1.0f - z) * n + z * h0j;
}

// ---------------------------------------------------------------------------
// k_att: per-session attention readout + swizzled P build (one block per b).
// P layout: Psw[b][f][lane][e], f=t*4+ks, lane=quad*16+m ->
// logical P row t*16+m, col ks*32+quad*8+e. Matches k_score A-frag loads.
__global__ void __launch_bounds__(256) k_att(const float* __restrict__ h1,
                    const float* __restrict__ W1T, const float* __restrict__ W1b,
                    const float* __restrict__ W2T, const float* __restrict__ W2b,
                    const float* __restrict__ WtT, const float* __restrict__ Wtb,
                    const float* __restrict__ qw, const float* __restrict__ qb,
                    const float* __restrict__ W3T, const float* __restrict__ W3b,
                    u16* __restrict__ P) {
    __shared__ float V[LL * Hh];
    __shared__ float Q2[LL * Hh];
    __shared__ float VTs[LL * Hh];
    __shared__ float Q1[Hh];
    __shared__ float AL[LL];
    __shared__ float SG[Hh];
    __shared__ float SH[Hh];
    const int b = blockIdx.x, tid = threadIdx.x;
    for (int idx = tid; idx < LL * Hh; idx += 256) V[idx] = h1[b * LL * Hh + idx];
    __syncthreads();
    for (int idx = tid; idx < LL * Hh; idx += 256) {
        int i = idx / Hh, j = idx - i * Hh;
        float a2 = 0, at = 0;
        for (int k = 0; k < Hh; ++k) {
            float vk = V[i * Hh + k];
            a2 += vk * W2T[k * Hh + j];
            at += vk * WtT[k * Hh + j];
        }
        Q2[idx] = a2 + W2b[j];
        VTs[idx] = at + Wtb[j];
    }
    if (tid < Hh) {
        float a1 = 0;
        for (int k = 0; k < Hh; ++k) a1 += V[(LL - 1) * Hh + k] * W1T[k * Hh + tid];
        Q1[tid] = a1 + W1b[tid];
    }
    __syncthreads();
    if (tid < LL) {
        float acc = 0;
        for (int j = 0; j < Hh; ++j)
            acc += sigmoidf_(Q1[j] + Q2[tid * Hh + j]) * qw[j];
        AL[tid] = acc + qb[0];
    }
    __syncthreads();
    if (tid < Hh) {
        float acc = 0;
#pragma unroll
        for (int l = 0; l < LL; ++l) acc += AL[l] * V[l * Hh + tid];
        SG[tid] = acc;
    }
    __syncthreads();
    if (tid < Hh) {
        float acc = W3b[tid];
        for (int k = 0; k < Hh; ++k) acc += V[(LL - 1) * Hh + k] * W3T[k * Hh + tid];
        for (int k = 0; k < Hh; ++k) acc += SG[k] * W3T[(Hh + k) * Hh + tid];
        SH[tid] = acc;
    }
    __syncthreads();
    // Swizzled P write: 12 frags x 64 lanes x 8 elems
    for (int w = tid; w < PFR * 64; w += 256) {
        int f = w >> 6, lane = w & 63;
        int t = f >> 2, ks = f & 3;
        int mm = lane & 15, qq = lane >> 4;
        int row = t * 16 + mm;
        int col0 = ks * 32 + qq * 8;
        short8 t8;
#pragma unroll
        for (int e = 0; e < 8; ++e) {
            int col = col0 + e;
            float v = 0.0f;
            if (col < Hh) {
                if      (row < 16) v = VTs[row * Hh + col];
                else if (row < 32) v = V[(row - 16) * Hh + col];
                else if (row == 32) v = SH[col];
            }
            t8[e] = (short)f2bf(v);
        }
        *(short8*)&P[((size_t)b * PFR + f) * 512 + lane * 8] = t8;
    }
}

// ---------------------------------------------------------------------------
// k_score v5: embed rows = register B-frags (loaded once); swizzled P panels
// staged into double-buffered LDS (flat 16B/lane copies, conflict-free both
// ways), single A[12] register set (low VGPR -> high occupancy), one barrier
// per b iteration. Math identical to R8 (correctness-proven).
__device__ __forceinline__ short8 load_efrag(const void* embed, bool bf, int j, int k0) {
    short8 v = {0, 0, 0, 0, 0, 0, 0, 0};
    if (j >= NNODE || k0 >= Hh) return v;
    if (bf) {
        const u16* row = (const u16*)embed + (size_t)j * Hh + k0;
        if (k0 + 8 <= Hh) {
            ushort4 a = *(const ushort4*)(row);
            ushort4 b = *(const ushort4*)(row + 4);
            v[0] = (short)a.x; v[1] = (short)a.y; v[2] = (short)a.z; v[3] = (short)a.w;
            v[4] = (short)b.x; v[5] = (short)b.y; v[6] = (short)b.z; v[7] = (short)b.w;
        } else {
            for (int e = 0; e < Hh - k0; ++e) v[e] = (short)row[e];
        }
    } else {
        const float* row = (const float*)embed + (size_t)j * Hh + k0;
        if (k0 + 8 <= Hh) {
            float4 a = *(const float4*)(row);
            float4 b = *(const float4*)(row + 4);
            v[0] = (short)f2bf(a.x); v[1] = (short)f2bf(a.y); v[2] = (short)f2bf(a.z); v[3] = (short)f2bf(a.w);
            v[4] = (short)f2bf(b.x); v[5] = (short)f2bf(b.y); v[6] = (short)f2bf(b.z); v[7] = (short)f2bf(b.w);
        } else {
            for (int e = 0; e < Hh - k0; ++e) v[e] = (short)f2bf(row[e]);
        }
    }
    return v;
}

__global__ void __launch_bounds__(256) k_score(const int* __restrict__ flag,
                                               const void* __restrict__ embed,
                                               const u16* __restrict__ P,
                                               void* __restrict__ out) {
    __shared__ alignas(16) u16 sPan[2][PPAN];    // 2 x 12288 B
    const int jb = blockIdx.x * 128;
    const int b0 = blockIdx.y * BPB;
    const int tid = threadIdx.x;
    const bool bf = (flag[0] != 0);
    const int wave = tid >> 6, lane = tid & 63;
    const int m = lane & 15, quad = lane >> 4;

    // B fragments: 2 groups of 16 embed rows per wave, loaded once.
    short8 Bf[2][4];
#pragma unroll
    for (int g = 0; g < 2; ++g)
#pragma unroll
        for (int ks = 0; ks < 4; ++ks)
            Bf[g][ks] = load_efrag(embed, bf, jb + wave * 32 + g * 16 + m, ks * 32 + quad * 8);

    // C/D orientation probe (m89-verified expectation: isH1 true).
    short8 pa = {0, 0, 0, 0, 0, 0, 0, 0};
    short8 pb = {0, 0, 0, 0, 0, 0, 0, 0};
    if (quad == 0) {
        pa[0] = (short)f2bf((float)m);
        pb[0] = (short)f2bf(1.0f);
    }
    f32x4 pd = (f32x4){0.0f, 0.0f, 0.0f, 0.0f};
    pd = __builtin_amdgcn_mfma_f32_16x16x32_bf16(pa, pb, pd, 0, 0, 0);
    const bool isH1 =
        (__builtin_amdgcn_readfirstlane(__float_as_uint(pd[1])) == 0x3f800000u);

    auto stage = [&](int b, u16* dst) {
        const uint4* s4 = (const uint4*)(P + (size_t)b * PPAN);   // 768 uint4
#pragma unroll
        for (int it = 0; it < 3; ++it) {
            int f = tid + it * 256;
            *(uint4*)&dst[f * 8] = s4[f];
        }
    };

    stage(b0, sPan[0]);
    int cur = 0;
    for (int bi = 0; bi < BPB; ++bi) {
        const int b = b0 + bi;
        __syncthreads();                          // sPan[cur] staged; prior reads done
        if (bi + 1 < BPB) stage(b + 1, sPan[cur ^ 1]);

        const u16* sp = sPan[cur];
        short8 A[PFR];
#pragma unroll
        for (int f = 0; f < PFR; ++f)
            A[f] = *(const short8*)&sp[f * 512 + lane * 8];

        f32x4 acc[2][3];
#pragma unroll
        for (int g = 0; g < 2; ++g)
#pragma unroll
            for (int t = 0; t < 3; ++t)
                acc[g][t] = (f32x4){0.0f, 0.0f, 0.0f, 0.0f};
#pragma unroll
        for (int ks = 0; ks < 4; ++ks)
#pragma unroll
            for (int g = 0; g < 2; ++g)
#pragma unroll
                for (int t = 0; t < 3; ++t)
                    acc[g][t] = __builtin_amdgcn_mfma_f32_16x16x32_bf16(A[t * 4 + ks], Bf[g][ks], acc[g][t], 0, 0, 0);

#pragma unroll
        for (int g = 0; g < 2; ++g) {
            if (isH1) {
                // col = lane&15 = n (embed row); row = quad*4+reg = P row
                float mx = fmaxf(fmaxf(acc[g][0][0], acc[g][0][1]), fmaxf(acc[g][0][2], acc[g][0][3]));
                mx = fmaxf(mx, __shfl_xor(mx, 16));
                mx = fmaxf(mx, __shfl_xor(mx, 32));
                float den = 0.0f, num = 0.0f;
#pragma unroll
                for (int r = 0; r < 4; ++r) {
                    float p = __expf(acc[g][0][r] - mx);
                    den += p;
                    num += p * acc[g][1][r];
                }
                den += __shfl_xor(den, 16); num += __shfl_xor(num, 16);
                den += __shfl_xor(den, 32); num += __shfl_xor(num, 32);
                if (quad == 0) {
                    int j = jb + wave * 32 + g * 16 + m;
                    if (j < NNODE) {
                        float z = acc[g][2][0] + num / den;    // sd: P row 0 of tile 2
                        if (bf) ((u16*)out)[(size_t)b * NNODE + j] = f2bf(z);
                        else    ((float*)out)[(size_t)b * NNODE + j] = z;
                    }
                }
            } else {
                float mx[4], den[4], num[4];
#pragma unroll
                for (int r = 0; r < 4; ++r) mx[r] = acc[g][0][r];
#pragma unroll
                for (int s = 1; s <= 8; s <<= 1)
#pragma unroll
                    for (int r = 0; r < 4; ++r) mx[r] = fmaxf(mx[r], __shfl_xor(mx[r], s));
#pragma unroll
                for (int r = 0; r < 4; ++r) {
                    float p = __expf(acc[g][0][r] - mx[r]);
                    den[r] = p;
                    num[r] = p * acc[g][1][r];
                }
#pragma unroll
                for (int s = 1; s <= 8; s <<= 1)
#pragma unroll
                    for (int r = 0; r < 4; ++r) {
                        den[r] += __shfl_xor(den[r], s);
                        num[r] += __shfl_xor(num[r], s);
                    }
                if (m == 0) {
#pragma unroll
                    for (int r = 0; r < 4; ++r) {
                        int j = jb + wave * 32 + g * 16 + quad * 4 + r;
                        if (j < NNODE) {
                            float z = acc[g][2][r] + num[r] / den[r];
                            if (bf) ((u16*)out)[(size_t)b * NNODE + j] = f2bf(z);
                            else    ((float*)out)[(size_t)b * NNODE + j] = z;
                        }
                    }
                }
            }
        }
        cur ^= 1;
    }
}

extern "C" void kernel_launch(void* const* d_in, const int* in_sizes, int n_in,
                              void* d_out, int out_size, void* d_ws, size_t ws_size,
                              hipStream_t stream) {
    const int* x      = (const int*)d_in[0];
    const int* ei     = (const int*)d_in[1];
    const void* ew    = d_in[2];
    // d_in[3] batch: unused by reference
    const void* embed = d_in[4];
    const void* ggc   = d_in[5];
    const void* wih   = d_in[6];
    const void* whh   = d_in[7];
    const void* bih   = d_in[8];
    const void* bhh   = d_in[9];
    const void* W1w   = d_in[10];
    const void* W1b   = d_in[11];
    const void* W2w   = d_in[12];
    const void* W2b   = d_in[13];
    const void* Wtw   = d_in[14];
    const void* Wtb   = d_in[15];
    const void* qw    = d_in[16];
    const void* qb    = d_in[17];
    const void* W3w   = d_in[18];
    const void* W3b   = d_in[19];
    float* ws = (float*)d_ws;
    int* flag = (int*)d_ws;          // ws[0]

    // ws layout (floats):
    //   [0..64)           flag + pad
    //   [64..64+123232)   fp32 weight region W (gru/att matrices TRANSPOSED)
    //   [D..D+299008)     data region with overlays:
    //     m   = D+0       (102400)  written k_gm, read k_scatter (dead after)
    //     agg = D+102400  (102400)  zeroed k_gm, scatter-add, read k_gru (dead after)
    //     h1  = D+0       (102400)  overlays dead m; written k_gru, read k_att
    //     P   = (u16*)(D+102400)    overlays dead agg; 393216 u16 = 196608 floats
    //           spans [D+102400, D+299008) — never overlaps live h1.
    float* W = ws + 64;
    float* ew_f  = W + 0;
    float* ggc_f = W + 2048;
    float* wihT  = W + 12048;
    float* whhT  = W + 42048;
    float* bih_f = W + 72048;
    float* bhh_f = W + 72352;
    float* W1T   = W + 72656;
    float* W1b_f = W + 82656;
    float* W2T   = W + 82768;
    float* W2b_f = W + 92768;
    float* WtT   = W + 92880;
    float* Wtb_f = W + 102880;
    float* qw_f  = W + 102992;
    float* qb_f  = W + 103104;
    float* W3T   = W + 103120;
    float* W3b_f = W + 123120;

    float* D     = ws + 123296;
    float* m     = D;
    float* agg   = D + 102400;
    float* h1    = D;                       // overlays dead m
    u16*   P     = (u16*)(D + 102400);      // overlays dead agg

    k_cvt    <<<dim3(482), dim3(256), 0, stream>>>(embed, flag, ew, ggc, wih, whh, bih, bhh,
                                                   W1w, W1b, W2w, W2b, Wtw, Wtb, qw, qb, W3w, W3b, W);
    k_gm     <<<dim3(128), dim3(256), 0, stream>>>(flag, x, embed, ggc_f, m, agg);
    k_scatter<<<dim3(800), dim3(256), 0, stream>>>(ei, ew_f, m, agg);
    k_gru    <<<dim3(400), dim3(256), 0, stream>>>(flag, x, embed, agg, wihT, whhT, bih_f, bhh_f, h1);
    k_att    <<<dim3(64),  dim3(256), 0, stream>>>(h1, W1T, W1b_f, W2T, W2b_f, WtT, Wtb_f,
                                                   qw_f, qb_f, W3T, W3b_f, P);
    k_score  <<<dim3((NNODE + 127) / 128, BSPL), dim3(256), 0, stream>>>(flag, embed, P, d_out);
}

// Round 10
// 234.612 us; speedup vs baseline: 1.1759x; 1.0277x over previous
//
#include <hip/hip_runtime.h>
#include <hip/hip_bf16.h>

// Problem constants (from reference)
#define Hh    100
#define NN    1024     // B*L
#define BB    64
#define LL    16
#define EE    2048
#define NNODE 40000

#define BSPL  8        // b-loop split across blockIdx.y
#define BPB   (BB / BSPL)
#define PFR   12       // fragments per panel: f = t*4+ks, t in 0..2, ks in 0..3
#define PPAN  (PFR * 64 * 8)   // u16 per panel (6144)

typedef unsigned short u16;
typedef __attribute__((ext_vector_type(8))) short short8;   // 8 bf16 = 4 VGPRs
typedef __attribute__((ext_vector_type(4))) float f32x4;    // MFMA C/D

__device__ __forceinline__ float bf2f(u16 u) {
    union { unsigned int i; float f; } v;
    v.i = ((unsigned int)u) << 16;
    return v.f;
}

__device__ __forceinline__ u16 f2bf(float f) {
    unsigned int x = __float_as_uint(f);
    unsigned int lsb = (x >> 16) & 1u;
    x += 0x7fffu + lsb;              // round-to-nearest-even
    return (u16)(x >> 16);
}

__device__ __forceinline__ float sigmoidf_(float x) {
    return 1.0f / (1.0f + expf(-x));
}

template <bool BF>
__device__ __forceinline__ float ldv(const void* p, size_t i) {
    if (BF) return bf2f(((const u16*)p)[i]);
    return ((const float*)p)[i];
}
__device__ __forceinline__ float ldvf(int flag, const void* p, size_t i) {
    return flag ? ldv<true>(p, i) : ldv<false>(p, i);
}

// ---------------------------------------------------------------------------
// k_cvt: per-block dtype self-detect + convert/transpose small float tensors
// to fp32 in ws (gru/att matrices TRANSPOSED for coalesced reads).
template <bool BF>
__device__ void cvt_impl(int t,
                         const void* ew, const void* ggc, const void* wih, const void* whh,
                         const void* bih, const void* bhh, const void* W1w, const void* W1b,
                         const void* W2w, const void* W2b, const void* Wtw, const void* Wtb,
                         const void* qw, const void* qb, const void* W3w, const void* W3b,
                         float* __restrict__ W) {
    const void* src; int si; int doff; int di;
    if      (t <   2048) { src = ew;  si = t;          doff = 0;      di = si; }
    else if (t <  12048) { src = ggc; si = t - 2048;   doff = 2048;   di = si; }                      // row-major (k_gm)
    else if (t <  42048) { src = wih; si = t - 12048;  doff = 12048;  di = (si % 100) * 300 + si / 100; }   // T
    else if (t <  72048) { src = whh; si = t - 42048;  doff = 42048;  di = (si % 100) * 300 + si / 100; }   // T
    else if (t <  72348) { src = bih; si = t - 72048;  doff = 72048;  di = si; }
    else if (t <  72648) { src = bhh; si = t - 72348;  doff = 72352;  di = si; }
    else if (t <  82648) { src = W1w; si = t - 72648;  doff = 72656;  di = (si % 100) * 100 + si / 100; }   // T
    else if (t <  82748) { src = W1b; si = t - 82648;  doff = 82656;  di = si; }
    else if (t <  92748) { src = W2w; si = t - 82748;  doff = 82768;  di = (si % 100) * 100 + si / 100; }   // T
    else if (t <  92848) { src = W2b; si = t - 92748;  doff = 92768;  di = si; }
    else if (t < 102848) { src = Wtw; si = t - 92848;  doff = 92880;  di = (si % 100) * 100 + si / 100; }   // T
    else if (t < 102948) { src = Wtb; si = t - 102848; doff = 102880; di = si; }
    else if (t < 103048) { src = qw;  si = t - 102948; doff = 102992; di = si; }
    else if (t < 103049) { src = qb;  si = t - 103048; doff = 103104; di = si; }
    else if (t < 123049) { src = W3w; si = t - 103049; doff = 103120; di = (si % 200) * 100 + si / 200; }   // T
    else                 { src = W3b; si = t - 123049; doff = 123120; di = si; }
    W[doff + di] = ldv<BF>(src, si);
}

__global__ void __launch_bounds__(256) k_cvt(const void* embed_raw, int* __restrict__ flag,
                      const void* ew, const void* ggc, const void* wih, const void* whh,
                      const void* bih, const void* bhh, const void* W1w, const void* W1b,
                      const void* W2w, const void* W2b, const void* Wtw, const void* Wtb,
                      const void* qw, const void* qb, const void* W3w, const void* W3b,
                      float* __restrict__ W) {
    __shared__ int cnt;
    if (threadIdx.x == 0) cnt = 0;
    __syncthreads();
    int bad = 0;
    const u16* eb = (const u16*)embed_raw;
    for (int i = threadIdx.x; i < 4096; i += 256) {
        float v = bf2f(eb[i]);
        if (!(fabsf(v) <= 0.5f)) bad++;   // counts NaN too
    }
    if (bad) atomicAdd(&cnt, bad);
    __syncthreads();
    const bool bf = (cnt == 0);
    if (blockIdx.x == 0 && threadIdx.x == 0) flag[0] = bf ? 1 : 0;
    int t = blockIdx.x * 256 + threadIdx.x;
    if (t >= 123149) return;
    if (bf) cvt_impl<true >(t, ew, ggc, wih, whh, bih, bhh, W1w, W1b, W2w, W2b, Wtw, Wtb, qw, qb, W3w, W3b, W);
    else    cvt_impl<false>(t, ew, ggc, wih, whh, bih, bhh, W1w, W1b, W2w, W2b, Wtw, Wtb, qw, qb, W3w, W3b, W);
}

// ---------------------------------------------------------------------------
// k_gm: fused embed-gather + m = h0 @ ggc, plus agg zero-init.
__global__ void __launch_bounds__(256) k_gm(const int* __restrict__ flag,
                                            const int* __restrict__ x,
                                            const void* __restrict__ embed,
                                            const float* __restrict__ ggc_w,
                                            float* __restrict__ m,
                                            float* __restrict__ agg) {
    __shared__ float W[Hh * Hh];
    __shared__ float H[8 * Hh];
    const int tid = threadIdx.x;
    const int fl = flag[0];
    const int r0 = blockIdx.x * 8;
    for (int idx = tid; idx < Hh * Hh; idx += 256) W[idx] = ggc_w[idx];
    for (int idx = tid; idx < 8 * Hh; idx += 256) {
        int i = idx / Hh, j = idx - i * Hh;
        H[idx] = ldvf(fl, embed, (size_t)x[r0 + i] * Hh + j);
    }
    for (int idx = tid; idx < 8 * Hh; idx += 256) agg[r0 * Hh + idx] = 0.0f;
    __syncthreads();
    for (int idx = tid; idx < 8 * Hh; idx += 256) {
        int i = idx / Hh, j = idx - i * Hh;
        float acc = 0.0f;
#pragma unroll 4
        for (int k = 0; k < Hh; ++k) acc += H[i * Hh + k] * W[k * Hh + j];
        m[(r0 + i) * Hh + j] = acc;
    }
}

// agg[dst[e]] += ew[e] * m[src[e]]
__global__ void k_scatter(const int* __restrict__ ei, const float* __restrict__ ew,
                          const float* __restrict__ m, float* __restrict__ agg) {
    int t = blockIdx.x * 256 + threadIdx.x;
    if (t >= EE * Hh) return;
    int e = t / Hh, j = t - e * Hh;
    int src = ei[e], dst = ei[EE + e];
    atomicAdd(&agg[dst * Hh + j], ew[e] * m[src * Hh + j]);
}

// GRU cell: h0 re-gathered from embed (no h0 buffer). Transposed weights ->
// coalesced; 400 blocks for latency hiding.
__global__ void k_gru(const int* __restrict__ flag, const int* __restrict__ x,
                      const void* __restrict__ embed,
                      const float* __restrict__ agg,
                      const float* __restrict__ wihT, const float* __restrict__ whhT,
                      const float* __restrict__ bih, const float* __restrict__ bhh,
                      float* __restrict__ h1) {
    int t = blockIdx.x * 256 + threadIdx.x;
    if (t >= NN * Hh) return;
    int i = t / Hh, j = t - i * Hh;
    const int fl = flag[0];
    const size_t erow = (size_t)x[i] * Hh;
    const float* ar = agg + i * Hh;
    float s_ir = bih[j], s_iz = bih[j + Hh], s_in = bih[j + 2 * Hh];
    float s_hr = bhh[j], s_hz = bhh[j + Hh], s_hn = bhh[j + 2 * Hh];
    float h0j = 0.0f;
    for (int k = 0; k < Hh; ++k) {
        float a = ar[k];
        float h = ldvf(fl, embed, erow + k);
        if (k == j) h0j = h;
        const float* wT = wihT + k * 300;
        const float* uT = whhT + k * 300;
        s_ir += a * wT[j];
        s_iz += a * wT[j + 100];
        s_in += a * wT[j + 200];
        s_hr += h * uT[j];
        s_hz += h * uT[j + 100];
        s_hn += h * uT[j + 200];
    }
    float r = sigmoidf_(s_ir + s_hr);
    float z = sigmoidf_(s_iz + s_hz);
    float n = tanhf(s_in + r * s_hn);
    h1[t] = (1.0f - z) * n + z * h0j;
}

// ---------------------------------------------------------------------------
// k_att: per-session attention readout + swizzled P build (one block per b).
// P layout: Psw[b][f][lane][e], f=t*4+ks, lane=quad*16+m ->
// logical P row t*16+m, col ks*32+quad*8+e. Matches k_score A-frag loads.
__global__ void __launch_bounds__(256) k_att(const float* __restrict__ h1,
                    const float* __restrict__ W1T, const float* __restrict__ W1b,
                    const float* __restrict__ W2T, const float* __restrict__ W2b,
                    const float* __restrict__ WtT, const float* __restrict__ Wtb,
                    const float* __restrict__ qw, const float* __restrict__ qb,
                    const float* __restrict__ W3T, const float* __restrict__ W3b,
                    u16* __restrict__ P) {
    __shared__ float V[LL * Hh];
    __shared__ float Q2[LL * Hh];
    __shared__ float VTs[LL * Hh];
    __shared__ float Q1[Hh];
    __shared__ float AL[LL];
    __shared__ float SG[Hh];
    __shared__ float SH[Hh];
    const int b = blockIdx.x, tid = threadIdx.x;
    for (int idx = tid; idx < LL * Hh; idx += 256) V[idx] = h1[b * LL * Hh + idx];
    __syncthreads();
    for (int idx = tid; idx < LL * Hh; idx += 256) {
        int i = idx / Hh, j = idx - i * Hh;
        float a2 = 0, at = 0;
        for (int k = 0; k < Hh; ++k) {
            float vk = V[i * Hh + k];
            a2 += vk * W2T[k * Hh + j];
            at += vk * WtT[k * Hh + j];
        }
        Q2[idx] = a2 + W2b[j];
        VTs[idx] = at + Wtb[j];
    }
    if (tid < Hh) {
        float a1 = 0;
        for (int k = 0; k < Hh; ++k) a1 += V[(LL - 1) * Hh + k] * W1T[k * Hh + tid];
        Q1[tid] = a1 + W1b[tid];
    }
    __syncthreads();
    if (tid < LL) {
        float acc = 0;
        for (int j = 0; j < Hh; ++j)
            acc += sigmoidf_(Q1[j] + Q2[tid * Hh + j]) * qw[j];
        AL[tid] = acc + qb[0];
    }
    __syncthreads();
    if (tid < Hh) {
        float acc = 0;
#pragma unroll
        for (int l = 0; l < LL; ++l) acc += AL[l] * V[l * Hh + tid];
        SG[tid] = acc;
    }
    __syncthreads();
    if (tid < Hh) {
        float acc = W3b[tid];
        for (int k = 0; k < Hh; ++k) acc += V[(LL - 1) * Hh + k] * W3T[k * Hh + tid];
        for (int k = 0; k < Hh; ++k) acc += SG[k] * W3T[(Hh + k) * Hh + tid];
        SH[tid] = acc;
    }
    __syncthreads();
    // Swizzled P write: 12 frags x 64 lanes x 8 elems
    for (int w = tid; w < PFR * 64; w += 256) {
        int f = w >> 6, lane = w & 63;
        int t = f >> 2, ks = f & 3;
        int mm = lane & 15, qq = lane >> 4;
        int row = t * 16 + mm;
        int col0 = ks * 32 + qq * 8;
        short8 t8;
#pragma unroll
        for (int e = 0; e < 8; ++e) {
            int col = col0 + e;
            float v = 0.0f;
            if (col < Hh) {
                if      (row < 16) v = VTs[row * Hh + col];
                else if (row < 32) v = V[(row - 16) * Hh + col];
                else if (row == 32) v = SH[col];
            }
            t8[e] = (short)f2bf(v);
        }
        *(short8*)&P[((size_t)b * PFR + f) * 512 + lane * 8] = t8;
    }
}

// ---------------------------------------------------------------------------
// k_score v6: register prefetch of next P panel is issued BEFORE compute and
// committed to the other LDS buffer AFTER compute (vmcnt wait overlaps the
// MFMAs) — one barrier per iter, global latency hidden. A-frags loaded per-t
// (low VGPR). Max-free softmax (|t| <= ~6, exp cannot overflow; identical
// normalized result).
__device__ __forceinline__ short8 load_efrag(const void* embed, bool bf, int j, int k0) {
    short8 v = {0, 0, 0, 0, 0, 0, 0, 0};
    if (j >= NNODE || k0 >= Hh) return v;
    if (bf) {
        const u16* row = (const u16*)embed + (size_t)j * Hh + k0;
        if (k0 + 8 <= Hh) {
            ushort4 a = *(const ushort4*)(row);
            ushort4 b = *(const ushort4*)(row + 4);
            v[0] = (short)a.x; v[1] = (short)a.y; v[2] = (short)a.z; v[3] = (short)a.w;
            v[4] = (short)b.x; v[5] = (short)b.y; v[6] = (short)b.z; v[7] = (short)b.w;
        } else {
            for (int e = 0; e < Hh - k0; ++e) v[e] = (short)row[e];
        }
    } else {
        const float* row = (const float*)embed + (size_t)j * Hh + k0;
        if (k0 + 8 <= Hh) {
            float4 a = *(const float4*)(row);
            float4 b = *(const float4*)(row + 4);
            v[0] = (short)f2bf(a.x); v[1] = (short)f2bf(a.y); v[2] = (short)f2bf(a.z); v[3] = (short)f2bf(a.w);
            v[4] = (short)f2bf(b.x); v[5] = (short)f2bf(b.y); v[6] = (short)f2bf(b.z); v[7] = (short)f2bf(b.w);
        } else {
            for (int e = 0; e < Hh - k0; ++e) v[e] = (short)f2bf(row[e]);
        }
    }
    return v;
}

__global__ void __launch_bounds__(256) k_score(const int* __restrict__ flag,
                                               const void* __restrict__ embed,
                                               const u16* __restrict__ P,
                                               void* __restrict__ out) {
    __shared__ alignas(16) u16 sPan[2][PPAN];    // 2 x 12288 B
    const int jb = blockIdx.x * 128;
    const int b0 = blockIdx.y * BPB;
    const int tid = threadIdx.x;
    const bool bf = (flag[0] != 0);
    const int wave = tid >> 6, lane = tid & 63;
    const int m = lane & 15, quad = lane >> 4;

    // B fragments: 2 groups of 16 embed rows per wave, loaded once.
    short8 Bf[2][4];
#pragma unroll
    for (int g = 0; g < 2; ++g)
#pragma unroll
        for (int ks = 0; ks < 4; ++ks)
            Bf[g][ks] = load_efrag(embed, bf, jb + wave * 32 + g * 16 + m, ks * 32 + quad * 8);

    // C/D orientation probe (m89-verified expectation: isH1 true).
    short8 pa = {0, 0, 0, 0, 0, 0, 0, 0};
    short8 pb = {0, 0, 0, 0, 0, 0, 0, 0};
    if (quad == 0) {
        pa[0] = (short)f2bf((float)m);
        pb[0] = (short)f2bf(1.0f);
    }
    f32x4 pd = (f32x4){0.0f, 0.0f, 0.0f, 0.0f};
    pd = __builtin_amdgcn_mfma_f32_16x16x32_bf16(pa, pb, pd, 0, 0, 0);
    const bool isH1 =
        (__builtin_amdgcn_readfirstlane(__float_as_uint(pd[1])) == 0x3f800000u);

    // Preload panel b0 -> LDS buffer 0
    {
        const uint4* s4 = (const uint4*)(P + (size_t)b0 * PPAN);   // 768 uint4
        uint4 g0 = s4[tid], g1 = s4[tid + 256], g2 = s4[tid + 512];
        uint4* d = (uint4*)sPan[0];
        d[tid] = g0; d[tid + 256] = g1; d[tid + 512] = g2;
    }
    __syncthreads();

    int cur = 0;
    for (int bi = 0; bi < BPB; ++bi) {
        const int b = b0 + bi;
        // Issue next-panel global loads (no wait — overlaps compute below)
        uint4 g0, g1, g2;
        if (bi + 1 < BPB) {
            const uint4* s4 = (const uint4*)(P + (size_t)(b + 1) * PPAN);
            g0 = s4[tid]; g1 = s4[tid + 256]; g2 = s4[tid + 512];
        }

        const u16* sp = sPan[cur];
        f32x4 acc[2][3];
#pragma unroll
        for (int g = 0; g < 2; ++g)
#pragma unroll
            for (int t = 0; t < 3; ++t)
                acc[g][t] = (f32x4){0.0f, 0.0f, 0.0f, 0.0f};
#pragma unroll
        for (int t = 0; t < 3; ++t) {
            short8 A0 = *(const short8*)&sp[(t * 4 + 0) * 512 + lane * 8];
            short8 A1 = *(const short8*)&sp[(t * 4 + 1) * 512 + lane * 8];
            short8 A2 = *(const short8*)&sp[(t * 4 + 2) * 512 + lane * 8];
            short8 A3 = *(const short8*)&sp[(t * 4 + 3) * 512 + lane * 8];
#pragma unroll
            for (int g = 0; g < 2; ++g) {
                acc[g][t] = __builtin_amdgcn_mfma_f32_16x16x32_bf16(A0, Bf[g][0], acc[g][t], 0, 0, 0);
                acc[g][t] = __builtin_amdgcn_mfma_f32_16x16x32_bf16(A1, Bf[g][1], acc[g][t], 0, 0, 0);
                acc[g][t] = __builtin_amdgcn_mfma_f32_16x16x32_bf16(A2, Bf[g][2], acc[g][t], 0, 0, 0);
                acc[g][t] = __builtin_amdgcn_mfma_f32_16x16x32_bf16(A3, Bf[g][3], acc[g][t], 0, 0, 0);
            }
        }

        // Epilogue (max-free softmax)
#pragma unroll
        for (int g = 0; g < 2; ++g) {
            if (isH1) {
                // col = lane&15 = n (embed row); row = quad*4+reg = P row
                float den = 0.0f, num = 0.0f;
#pragma unroll
                for (int r = 0; r < 4; ++r) {
                    float p = __expf(acc[g][0][r]);
                    den += p;
                    num += p * acc[g][1][r];
                }
                den += __shfl_xor(den, 16); num += __shfl_xor(num, 16);
                den += __shfl_xor(den, 32); num += __shfl_xor(num, 32);
                if (quad == 0) {
                    int j = jb + wave * 32 + g * 16 + m;
                    if (j < NNODE) {
                        float z = acc[g][2][0] + num / den;    // sd: P row 0 of tile 2
                        if (bf) ((u16*)out)[(size_t)b * NNODE + j] = f2bf(z);
                        else    ((float*)out)[(size_t)b * NNODE + j] = z;
                    }
                }
            } else {
                float den[4], num[4];
#pragma unroll
                for (int r = 0; r < 4; ++r) {
                    float p = __expf(acc[g][0][r]);
                    den[r] = p;
                    num[r] = p * acc[g][1][r];
                }
#pragma unroll
                for (int s = 1; s <= 8; s <<= 1)
#pragma unroll
                    for (int r = 0; r < 4; ++r) {
                        den[r] += __shfl_xor(den[r], s);
                        num[r] += __shfl_xor(num[r], s);
                    }
                if (m == 0) {
#pragma unroll
                    for (int r = 0; r < 4; ++r) {
                        int j = jb + wave * 32 + g * 16 + quad * 4 + r;
                        if (j < NNODE) {
                            float z = acc[g][2][r] + num[r] / den[r];
                            if (bf) ((u16*)out)[(size_t)b * NNODE + j] = f2bf(z);
                            else    ((float*)out)[(size_t)b * NNODE + j] = z;
                        }
                    }
                }
            }
        }

        // Commit prefetched panel to the other buffer (vmcnt wait lands here,
        // after compute) then single barrier.
        if (bi + 1 < BPB) {
            uint4* d = (uint4*)sPan[cur ^ 1];
            d[tid] = g0; d[tid + 256] = g1; d[tid + 512] = g2;
        }
        __syncthreads();
        cur ^= 1;
    }
}

extern "C" void kernel_launch(void* const* d_in, const int* in_sizes, int n_in,
                              void* d_out, int out_size, void* d_ws, size_t ws_size,
                              hipStream_t stream) {
    const int* x      = (const int*)d_in[0];
    const int* ei     = (const int*)d_in[1];
    const void* ew    = d_in[2];
    // d_in[3] batch: unused by reference
    const void* embed = d_in[4];
    const void* ggc   = d_in[5];
    const void* wih   = d_in[6];
    const void* whh   = d_in[7];
    const void* bih   = d_in[8];
    const void* bhh   = d_in[9];
    const void* W1w   = d_in[10];
    const void* W1b   = d_in[11];
    const void* W2w   = d_in[12];
    const void* W2b   = d_in[13];
    const void* Wtw   = d_in[14];
    const void* Wtb   = d_in[15];
    const void* qw    = d_in[16];
    const void* qb    = d_in[17];
    const void* W3w   = d_in[18];
    const void* W3b   = d_in[19];
    float* ws = (float*)d_ws;
    int* flag = (int*)d_ws;          // ws[0]

    // ws layout (floats):
    //   [0..64)           flag + pad
    //   [64..64+123232)   fp32 weight region W (gru/att matrices TRANSPOSED)
    //   [D..D+299008)     data region with overlays:
    //     m   = D+0       (102400)  written k_gm, read k_scatter (dead after)
    //     agg = D+102400  (102400)  zeroed k_gm, scatter-add, read k_gru (dead after)
    //     h1  = D+0       (102400)  overlays dead m; written k_gru, read k_att
    //     P   = (u16*)(D+102400)    overlays dead agg; never overlaps live h1.
    float* W = ws + 64;
    float* ew_f  = W + 0;
    float* ggc_f = W + 2048;
    float* wihT  = W + 12048;
    float* whhT  = W + 42048;
    float* bih_f = W + 72048;
    float* bhh_f = W + 72352;
    float* W1T   = W + 72656;
    float* W1b_f = W + 82656;
    float* W2T   = W + 82768;
    float* W2b_f = W + 92768;
    float* WtT   = W + 92880;
    float* Wtb_f = W + 102880;
    float* qw_f  = W + 102992;
    float* qb_f  = W + 103104;
    float* W3T   = W + 103120;
    float* W3b_f = W + 123120;

    float* D     = ws + 123296;
    float* m     = D;
    float* agg   = D + 102400;
    float* h1    = D;                       // overlays dead m
    u16*   P     = (u16*)(D + 102400);      // overlays dead agg

    k_cvt    <<<dim3(482), dim3(256), 0, stream>>>(embed, flag, ew, ggc, wih, whh, bih, bhh,
                                                   W1w, W1b, W2w, W2b, Wtw, Wtb, qw, qb, W3w, W3b, W);
    k_gm     <<<dim3(128), dim3(256), 0, stream>>>(flag, x, embed, ggc_f, m, agg);
    k_scatter<<<dim3(800), dim3(256), 0, stream>>>(ei, ew_f, m, agg);
    k_gru    <<<dim3(400), dim3(256), 0, stream>>>(flag, x, embed, agg, wihT, whhT, bih_f, bhh_f, h1);
    k_att    <<<dim3(64),  dim3(256), 0, stream>>>(h1, W1T, W1b_f, W2T, W2b_f, WtT, Wtb_f,
                                                   qw_f, qb_f, W3T, W3b_f, P);
    k_score  <<<dim3((NNODE + 127) / 128, BSPL), dim3(256), 0, stream>>>(flag, embed, P, d_out);
}